// Round 9
// baseline (47.380 us; speedup 1.0000x reference)
//
#include <hip/hip_runtime.h>
#include <math.h>

#define NN   96
#define NPOS (96*96)   // 9216
#define BB   32
#define KV   1024
#define KA   2048
#define POSB 32              // positions per ext block
#define PBLK (NPOS/POSB)     // 288 pos-tiles per modality

// ws layout (float offsets) — no split-K partials anymore
#define EXTV_OFF 0
#define EXTA_OFF (BB*NPOS)                 // 294912
#define CPT_OFF  (2*BB*NPOS)               // 589824
#define AFV_OFF  (CPT_OFF + 6*NPOS)        // 645120 (16B aligned)
#define AFV_SLOTS ((KV/32)*2*64)           // 4096 slots of 16B
#define AFA_OFF  (AFV_OFF + AFV_SLOTS*4)   // 661504
#define AFA_SLOTS ((KA/32)*2*64)           // 8192
// total ws ≈ 2.8 MB

typedef __bf16 bf16x8 __attribute__((ext_vector_type(8)));
typedef float  f32x4  __attribute__((ext_vector_type(4)));

// ---------------- nb (separable DoG) + vid/aud -> bf16 A-fragment pack ----------------
__global__ __launch_bounds__(256) void nbT_kernel(
    const float* __restrict__ na_v, const float* __restrict__ na_a,
    const float* __restrict__ na_m, const float* __restrict__ video,
    const float* __restrict__ audio, float* __restrict__ ws)
{
    __shared__ float G[96][100];
    __shared__ float act_s[96][100];
    __shared__ float T1t[24][100];

    if (blockIdx.x >= 24) {
        // A-fragment pack: A[16x32] lane layout row=l&15, k=(l>>4)*8+j
        const int e = (blockIdx.x - 24) * 256 + threadIdx.x;   // 0..12287
        const float* src; bf16x8* dst; int K, el;
        if (e < AFV_SLOTS) { src = video; K = KV; dst = (bf16x8*)(ws + AFV_OFF); el = e; }
        else               { src = audio; K = KA; dst = (bf16x8*)(ws + AFA_OFF); el = e - AFV_SLOTS; }
        const int l  = el & 63;
        const int hb = (el >> 6) & 1;
        const int sg = el >> 7;
        const int b  = hb * 16 + (l & 15);
        const int k0 = sg * 32 + ((l >> 4) << 3);
        const float4 f0 = *(const float4*)&src[(size_t)b * K + k0];
        const float4 f1 = *(const float4*)&src[(size_t)b * K + k0 + 4];
        bf16x8 v;
        v[0] = (__bf16)f0.x; v[1] = (__bf16)f0.y; v[2] = (__bf16)f0.z; v[3] = (__bf16)f0.w;
        v[4] = (__bf16)f1.x; v[5] = (__bf16)f1.y; v[6] = (__bf16)f1.z; v[7] = (__bf16)f1.w;
        dst[el] = v;
        return;
    }

    const int c  = blockIdx.x >> 2;
    const int js = (blockIdx.x & 3) * 24;
    float l, s;
    if      (c == 0) { l =  1.60f; s = 3.5f;  }
    else if (c == 1) { l = -1.23f; s = 6.3f;  }
    else if (c == 2) { l =  1.00f; s = 5.3f;  }
    else if (c == 3) { l = -0.80f; s = 11.8f; }
    else if (c == 4) { l =  3.80f; s = 3.5f;  }
    else             { l = -3.30f; s = 6.2f;  }
    const float s2 = s * s;
    const int f = c >> 1;
    const float* act = (f == 0) ? na_v : (f == 1) ? na_a : na_m;
    const int tid = threadIdx.x;
    float* cpt = ws + CPT_OFF;

    for (int idx = tid; idx < 9216; idx += 256) {
        int j = idx / 96, k = idx - j * 96;
        int d = abs(j - k); d = min(d, 96 - d);
        G[j][k]     = __expf(-0.5f * (float)(d * d) * s2);
        act_s[j][k] = act[idx];
    }
    __syncthreads();

    const int hg3 = (tid >> 3) * 3;
    const int jl3 = (tid & 7) * 3;

    float t1[3][3] = {};
    for (int k0 = 0; k0 < 96; k0 += 4) {
        float4 av[3], gv[3];
        #pragma unroll
        for (int r = 0; r < 3; r++) {
            av[r] = *(const float4*)&act_s[hg3 + r][k0];
            gv[r] = *(const float4*)&G[js + jl3 + r][k0];
        }
        #pragma unroll
        for (int hh = 0; hh < 3; hh++)
            #pragma unroll
            for (int jj = 0; jj < 3; jj++)
                t1[hh][jj] += av[hh].x * gv[jj].x + av[hh].y * gv[jj].y
                            + av[hh].z * gv[jj].z + av[hh].w * gv[jj].w;
    }
    #pragma unroll
    for (int hh = 0; hh < 3; hh++)
        #pragma unroll
        for (int jj = 0; jj < 3; jj++)
            T1t[jl3 + jj][hg3 + hh] = t1[hh][jj];
    __syncthreads();

    float o[3][3] = {};
    for (int h0 = 0; h0 < 96; h0 += 4) {
        float4 gv[3], tv[3];
        #pragma unroll
        for (int r = 0; r < 3; r++) {
            gv[r] = *(const float4*)&G[hg3 + r][h0];
            tv[r] = *(const float4*)&T1t[jl3 + r][h0];
        }
        #pragma unroll
        for (int ii = 0; ii < 3; ii++)
            #pragma unroll
            for (int jj = 0; jj < 3; jj++)
                o[ii][jj] += gv[ii].x * tv[jj].x + gv[ii].y * tv[jj].y
                           + gv[ii].z * tv[jj].z + gv[ii].w * tv[jj].w;
    }
    #pragma unroll
    for (int ii = 0; ii < 3; ii++)
        #pragma unroll
        for (int jj = 0; jj < 3; jj++)
            cpt[c * NPOS + (hg3 + ii) * 96 + (js + jl3 + jj)] = l * o[ii][jj];
}

// ---------------- ext GEMM: DMA-pipelined MFMA (T3/T4-lite) ----------------
// Block = 32 pos x 32 batch, full-K loop (A:64 steps, V:32), 4 waves = C
// quadrants. Per step each wave issues 2 global_load_lds (1KB rf quarter +
// 1KB af half, dup). Depth-4 buffers, counted s_waitcnt vmcnt(6) (never 0),
// raw s_barrier. rf source pre-swizzled so linear DMA write gives XOR-swizzled
// LDS (2-way = free on strided ds_read_b128). Compute phase: 3 ds_read + cvt
// + 1 MFMA — zero global loads (avoids in-order vmcnt drain).
__global__ __launch_bounds__(256) void ext_mfma(
    const float* __restrict__ rf_v, const float* __restrict__ rf_a,
    float* __restrict__ ws)
{
    __shared__ float lds[4 * 1536];   // 4 bufs x (1024 rf + 512 af) floats = 24 KB
    const int bid = blockIdx.x;
    const float* rf; const bf16x8* af; float* ext; int K, NS, pt;
    if (bid < PBLK) {                 // audio first (long blocks start early)
        pt = bid; rf = rf_a; K = KA; NS = KA / 32;
        af  = (const bf16x8*)(ws + AFA_OFF);
        ext = ws + EXTA_OFF;
    } else {
        pt = bid - PBLK; rf = rf_v; K = KV; NS = KV / 32;
        af  = (const bf16x8*)(ws + AFV_OFF);
        ext = ws + EXTV_OFF;
    }
    const int tid = threadIdx.x;
    const int l  = tid & 63, w = tid >> 6;
    const int ph = w & 1, bh = w >> 1;   // C quadrant: pos-half, batch-half

    // stage-source lane params (pre-swizzled k-chunk)
    const int srow = w * 8 + (l >> 3);               // LDS rf row this lane feeds
    const int kc   = (l & 7) ^ ((l >> 3) & 7);       // k-chunk at LDS slot l&7
    const float*  gsrc0 = rf + (size_t)(pt * 32 + srow) * K + kc * 4;
    const bf16x8* asrc0 = af + (w & 1) * 64 + l;

    char* ldsc = (char*)lds;
    const int rf_dst = w * 1024;                 // within buf
    const int af_dst = 4096 + (w & 1) * 1024;

    // reader lane params
    const int rrow  = ph * 16 + (l & 15);
    const int c0    = (l >> 4) * 2;
    const int roff0 = rrow * 128 + ((c0       ^ (rrow & 7)) * 16);
    const int roff1 = rrow * 128 + (((c0 + 1) ^ (rrow & 7)) * 16);
    const int aoff  = 4096 + bh * 1024 + l * 16;

#define STAGE(tt, dd)                                                         \
    do {                                                                      \
        const int t_ = (tt) < NS ? (tt) : NS - 1;                             \
        __builtin_amdgcn_global_load_lds(                                     \
            (const __attribute__((address_space(1))) void*)(gsrc0 + t_ * 32), \
            (__attribute__((address_space(3))) void*)(ldsc + (dd) * 6144 + rf_dst), \
            16, 0, 0);                                                        \
        __builtin_amdgcn_global_load_lds(                                     \
            (const __attribute__((address_space(1))) void*)(asrc0 + t_ * 128),\
            (__attribute__((address_space(3))) void*)(ldsc + (dd) * 6144 + af_dst), \
            16, 0, 0);                                                        \
    } while (0)

    STAGE(0, 0); STAGE(1, 1); STAGE(2, 2); STAGE(3, 3);

    f32x4 acc = {0.f, 0.f, 0.f, 0.f};
    for (int t = 0; t < NS; ++t) {
        const int d = t & 3;
        const char* buf = ldsc + d * 6144;
        asm volatile("s_waitcnt vmcnt(6)" ::: "memory");   // buf d landed (own quarter)
        __builtin_amdgcn_s_barrier();                      // all quarters landed
        __builtin_amdgcn_sched_barrier(0);
        f32x4  b0 = *(const f32x4*)(buf + roff0);
        f32x4  b1 = *(const f32x4*)(buf + roff1);
        bf16x8 av = *(const bf16x8*)(buf + aoff);
        bf16x8 bv;
        bv[0] = (__bf16)b0[0]; bv[1] = (__bf16)b0[1]; bv[2] = (__bf16)b0[2]; bv[3] = (__bf16)b0[3];
        bv[4] = (__bf16)b1[0]; bv[5] = (__bf16)b1[1]; bv[6] = (__bf16)b1[2]; bv[7] = (__bf16)b1[3];
        acc = __builtin_amdgcn_mfma_f32_16x16x32_bf16(av, bv, acc, 0, 0, 0);
        __builtin_amdgcn_sched_barrier(0);
        __builtin_amdgcn_s_barrier();                      // all done reading buf d
        __builtin_amdgcn_sched_barrier(0);
        STAGE(t + 4, d);                                   // refill the freed buffer
    }
#undef STAGE

    // C/D: col(pos) = lane&15, row(batch) = (lane>>4)*4 + reg
    const int pcol  = pt * 32 + ph * 16 + (l & 15);
    const int brow0 = bh * 16 + (l >> 4) * 4;
    #pragma unroll
    for (int r = 0; r < 4; ++r)
        ext[(size_t)(brow0 + r) * NPOS + pcol] = acc[r];
}

// ---------------- combine: ext + cpt + sigmoid dynamics ----------------
__global__ __launch_bounds__(256) void combine_kernel(
    const float* __restrict__ na_v, const float* __restrict__ na_a,
    const float* __restrict__ na_m, const float* __restrict__ ws,
    float* __restrict__ out)
{
    const int npq = NPOS >> 2;
    const int t = blockIdx.x * 256 + threadIdx.x;
    if (t >= BB * npq) return;
    const int b  = t / npq;
    const int p0 = (t - b * npq) << 2;

    float4 ev = *(const float4*)&ws[EXTV_OFF + (size_t)b * NPOS + p0];
    float4 ea = *(const float4*)&ws[EXTA_OFF + (size_t)b * NPOS + p0];
    const float* cpt = ws + CPT_OFF;
    float4 q0 = *(const float4*)&cpt[0 * NPOS + p0];
    float4 q1 = *(const float4*)&cpt[1 * NPOS + p0];
    float4 q2 = *(const float4*)&cpt[2 * NPOS + p0];
    float4 q3 = *(const float4*)&cpt[3 * NPOS + p0];
    float4 q4 = *(const float4*)&cpt[4 * NPOS + p0];
    float4 q5 = *(const float4*)&cpt[5 * NPOS + p0];
    float4 nv = *(const float4*)&na_v[p0];
    float4 na = *(const float4*)&na_a[p0];
    float4 nm = *(const float4*)&na_m[p0];

    float evs[4] = {ev.x, ev.y, ev.z, ev.w};
    float eas[4] = {ea.x, ea.y, ea.z, ea.w};
    float nbv[4] = {q0.x + q1.x, q0.y + q1.y, q0.z + q1.z, q0.w + q1.w};
    float nba[4] = {q2.x + q3.x, q2.y + q3.y, q2.z + q3.z, q2.w + q3.w};
    float nbm[4] = {q4.x + q5.x, q4.y + q5.y, q4.z + q5.z, q4.w + q5.w};
    float nvs[4] = {nv.x, nv.y, nv.z, nv.w};
    float nas[4] = {na.x, na.y, na.z, na.w};
    float nms[4] = {nm.x, nm.y, nm.z, nm.w};

    float4 o;
    float* os = (float*)&o;
    #pragma unroll
    for (int u = 0; u < 4; u++) {
        const float xv = (evs[u] + nbv[u] - 3.0f + nms[u]) * 0.3f;
        const float nav_new = nvs[u] * (2.f / 3.f) + (1.f / 3.f) / (1.f + __expf(-xv));
        const float xa = (eas[u] + nba[u] - 3.0f + nms[u]) * 0.3f;
        const float naa_new = nas[u] * (2.f / 3.f) + (1.f / 3.f) / (1.f + __expf(-xa));
        const float xm = (7.0f * nav_new + 3.0f * naa_new + nbm[u] - 3.0f) * 0.3f;
        os[u] = nms[u] * (2.f / 3.f) + (1.f / 3.f) / (1.f + __expf(-xm));
    }
    *(float4*)&out[(size_t)b * NPOS + p0] = o;
}

extern "C" void kernel_launch(void* const* d_in, const int* in_sizes, int n_in,
                              void* d_out, int out_size, void* d_ws, size_t ws_size,
                              hipStream_t stream) {
    const float* video = (const float*)d_in[0];
    const float* audio = (const float*)d_in[1];
    const float* rf_v  = (const float*)d_in[2];
    const float* rf_a  = (const float*)d_in[3];
    const float* na_v  = (const float*)d_in[4];
    const float* na_a  = (const float*)d_in[5];
    const float* na_m  = (const float*)d_in[6];
    float* ws  = (float*)d_ws;
    float* out = (float*)d_out;

    nbT_kernel<<<72, 256, 0, stream>>>(na_v, na_a, na_m, video, audio, ws);
    ext_mfma<<<2 * PBLK, 256, 0, stream>>>(rf_v, rf_a, ws);
    combine_kernel<<<(BB * NPOS / 4 + 255) / 256, 256, 0, stream>>>(
        na_v, na_a, na_m, ws, out);
}

// Round 10
// 40.102 us; speedup vs baseline: 1.1815x; 1.1815x over previous
//
#include <hip/hip_runtime.h>
#include <math.h>

#define NN   96
#define NPOS (96*96)   // 9216
#define BB   32
#define KV   1024
#define KA   2048

// jobs: uniform K-chunk of 1024 (32 steps). audio = 2 chunks, video = 1.
// 16 positions per 1-wave block -> 576 blocks per modality-chunk, 1728 total.
#define JOBS_A (2*576)

// ws layout (float offsets)
#define EXTV_OFF  0
#define EXTA0_OFF (BB*NPOS)            // 294912
#define EXTA1_OFF (2*BB*NPOS)          // 589824
#define CPT_OFF   (3*BB*NPOS)          // 884736
#define AFV_OFF   (CPT_OFF + 6*NPOS)   // 940032
#define AFV_SLOTS ((KV/32)*2*64)       // 4096 16B-slots
#define AFA_OFF   (AFV_OFF + AFV_SLOTS*4)  // 956416
#define AFA_SLOTS ((KA/32)*2*64)       // 8192
// total ws ~ 3.96 MB

typedef __bf16 bf16x8 __attribute__((ext_vector_type(8)));
typedef float  f32x4  __attribute__((ext_vector_type(4)));
typedef const __attribute__((address_space(1))) void* gas1_t;
typedef __attribute__((address_space(3))) void*       las3_t;
typedef const __attribute__((address_space(3))) char* lds3c_t;

// ---------------- nb (separable DoG) + vid/aud -> bf16 A-fragment pack ----------------
__global__ __launch_bounds__(256) void nbT_kernel(
    const float* __restrict__ na_v, const float* __restrict__ na_a,
    const float* __restrict__ na_m, const float* __restrict__ video,
    const float* __restrict__ audio, float* __restrict__ ws)
{
    __shared__ float G[96][100];
    __shared__ float act_s[96][100];
    __shared__ float T1t[24][100];

    if (blockIdx.x >= 24) {
        // A-fragment pack: A[16x32] lane layout row=l&15, k=(l>>4)*8+j
        const int e = (blockIdx.x - 24) * 256 + threadIdx.x;   // 0..12287
        const float* src; bf16x8* dst; int K, el;
        if (e < AFV_SLOTS) { src = video; K = KV; dst = (bf16x8*)(ws + AFV_OFF); el = e; }
        else               { src = audio; K = KA; dst = (bf16x8*)(ws + AFA_OFF); el = e - AFV_SLOTS; }
        const int l  = el & 63;
        const int hb = (el >> 6) & 1;
        const int sg = el >> 7;
        const int b  = hb * 16 + (l & 15);
        const int k0 = sg * 32 + ((l >> 4) << 3);
        const float4 f0 = *(const float4*)&src[(size_t)b * K + k0];
        const float4 f1 = *(const float4*)&src[(size_t)b * K + k0 + 4];
        bf16x8 v;
        v[0] = (__bf16)f0.x; v[1] = (__bf16)f0.y; v[2] = (__bf16)f0.z; v[3] = (__bf16)f0.w;
        v[4] = (__bf16)f1.x; v[5] = (__bf16)f1.y; v[6] = (__bf16)f1.z; v[7] = (__bf16)f1.w;
        dst[el] = v;
        return;
    }

    const int c  = blockIdx.x >> 2;
    const int js = (blockIdx.x & 3) * 24;
    float l, s;
    if      (c == 0) { l =  1.60f; s = 3.5f;  }
    else if (c == 1) { l = -1.23f; s = 6.3f;  }
    else if (c == 2) { l =  1.00f; s = 5.3f;  }
    else if (c == 3) { l = -0.80f; s = 11.8f; }
    else if (c == 4) { l =  3.80f; s = 3.5f;  }
    else             { l = -3.30f; s = 6.2f;  }
    const float s2 = s * s;
    const int f = c >> 1;
    const float* act = (f == 0) ? na_v : (f == 1) ? na_a : na_m;
    const int tid = threadIdx.x;
    float* cpt = ws + CPT_OFF;

    for (int idx = tid; idx < 9216; idx += 256) {
        int j = idx / 96, k = idx - j * 96;
        int d = abs(j - k); d = min(d, 96 - d);
        G[j][k]     = __expf(-0.5f * (float)(d * d) * s2);
        act_s[j][k] = act[idx];
    }
    __syncthreads();

    const int hg3 = (tid >> 3) * 3;
    const int jl3 = (tid & 7) * 3;

    float t1[3][3] = {};
    for (int k0 = 0; k0 < 96; k0 += 4) {
        float4 av[3], gv[3];
        #pragma unroll
        for (int r = 0; r < 3; r++) {
            av[r] = *(const float4*)&act_s[hg3 + r][k0];
            gv[r] = *(const float4*)&G[js + jl3 + r][k0];
        }
        #pragma unroll
        for (int hh = 0; hh < 3; hh++)
            #pragma unroll
            for (int jj = 0; jj < 3; jj++)
                t1[hh][jj] += av[hh].x * gv[jj].x + av[hh].y * gv[jj].y
                            + av[hh].z * gv[jj].z + av[hh].w * gv[jj].w;
    }
    #pragma unroll
    for (int hh = 0; hh < 3; hh++)
        #pragma unroll
        for (int jj = 0; jj < 3; jj++)
            T1t[jl3 + jj][hg3 + hh] = t1[hh][jj];
    __syncthreads();

    float o[3][3] = {};
    for (int h0 = 0; h0 < 96; h0 += 4) {
        float4 gv[3], tv[3];
        #pragma unroll
        for (int r = 0; r < 3; r++) {
            gv[r] = *(const float4*)&G[hg3 + r][h0];
            tv[r] = *(const float4*)&T1t[jl3 + r][h0];
        }
        #pragma unroll
        for (int ii = 0; ii < 3; ii++)
            #pragma unroll
            for (int jj = 0; jj < 3; jj++)
                o[ii][jj] += gv[ii].x * tv[jj].x + gv[ii].y * tv[jj].y
                           + gv[ii].z * tv[jj].z + gv[ii].w * tv[jj].w;
    }
    #pragma unroll
    for (int ii = 0; ii < 3; ii++)
        #pragma unroll
        for (int jj = 0; jj < 3; jj++)
            cpt[c * NPOS + (hg3 + ii) * 96 + (js + jl3 + jj)] = l * o[ii][jj];
}

// ---------------- ext GEMM: wave-private DMA pipeline, zero barriers ----------------
// 1 wave/block, 16 pos x 32 batch x 1024 k (32 steps). Per step 4 DMA
// (rf 2KB + af 2KB) into depth-4 private buffers; steady-state
// s_waitcnt vmcnt(12), epilogue 12/8/4/0 — never a drain. LDS reads are
// inline-asm ds_read_b128 so the compiler's legalizer can't inject vmcnt(0)
// (the r9 killer). lgkmcnt(0)+sched_barrier(0) fence per guide rule #18.
// rf source chunk pre-XOR'd so linear DMA writes a swizzled, bank-balanced
// layout for the strided read.
__global__ __launch_bounds__(64) void ext_mfma(
    const float* __restrict__ rf_v, const float* __restrict__ rf_a,
    float* __restrict__ ws)
{
    __shared__ char lds[16384];          // 4 bufs x (2KB rf + 2KB af)
    char* ldsc = (char*)lds;
    const int bid = blockIdx.x;
    const int l   = threadIdx.x;

    const float* rf; const bf16x8* af; float* ext; int K, kb, pt;
    if (bid < JOBS_A) {
        const int c = bid / 576; pt = bid - c * 576;
        rf = rf_a; K = KA; kb = c << 10;
        af  = (const bf16x8*)(ws + AFA_OFF);
        ext = ws + EXTA0_OFF + c * (BB * NPOS);
    } else {
        pt = bid - JOBS_A; rf = rf_v; K = KV; kb = 0;
        af  = (const bf16x8*)(ws + AFV_OFF);
        ext = ws + EXTV_OFF;
    }
    const int p0 = pt << 4;

    // DMA source lanes: rf0 -> rows 0-7, rf1 -> rows 8-15 of the pos tile;
    // chunk csrc = (l&7) ^ (row&7) pre-applies the LDS swizzle.
    const int r8   = l >> 3;
    const int csrc = (l & 7) ^ (r8 & 7);
    const float*  rf0 = rf + (size_t)(p0 + r8) * K + kb + csrc * 4;
    const float*  rf1 = rf0 + (size_t)8 * K;
    const bf16x8* afA = af + (kb >> 5) * 128 + l;
    const bf16x8* afB = afA + 64;

    // read lanes: row = l&15 (position), g = l>>4 (k-octet)
    const int row   = l & 15, g = l >> 4;
    const int roffA = row * 128 + ((((g << 1)    ) ^ (row & 7)) << 4);
    const int roffB = row * 128 + ((((g << 1) | 1) ^ (row & 7)) << 4);
    const int aoff  = l * 16;

#define STAGE(tt, dd)                                                          \
    do {                                                                       \
        const int t_ = (tt);                                                   \
        __builtin_amdgcn_global_load_lds((gas1_t)(rf0 + t_ * 32),              \
            (las3_t)(ldsc + (dd) * 4096), 16, 0, 0);                           \
        __builtin_amdgcn_global_load_lds((gas1_t)(rf1 + t_ * 32),              \
            (las3_t)(ldsc + (dd) * 4096 + 1024), 16, 0, 0);                    \
        __builtin_amdgcn_global_load_lds((gas1_t)(afA + t_ * 128),             \
            (las3_t)(ldsc + (dd) * 4096 + 2048), 16, 0, 0);                    \
        __builtin_amdgcn_global_load_lds((gas1_t)(afB + t_ * 128),             \
            (las3_t)(ldsc + (dd) * 4096 + 3072), 16, 0, 0);                    \
    } while (0)

#define ITER(tt, dd, WAIT, DO_STAGE)                                           \
    {                                                                          \
        asm volatile("s_waitcnt vmcnt(" #WAIT ")");                            \
        f32x4 rA, rB; bf16x8 av0, av1;                                         \
        asm volatile("ds_read_b128 %0, %1" : "=v"(rA)                          \
                     : "v"((lds3c_t)(ldsc + (dd) * 4096 + roffA)));            \
        asm volatile("ds_read_b128 %0, %1" : "=v"(rB)                          \
                     : "v"((lds3c_t)(ldsc + (dd) * 4096 + roffB)));            \
        asm volatile("ds_read_b128 %0, %1" : "=v"(av0)                         \
                     : "v"((lds3c_t)(ldsc + (dd) * 4096 + 2048 + aoff)));      \
        asm volatile("ds_read_b128 %0, %1" : "=v"(av1)                         \
                     : "v"((lds3c_t)(ldsc + (dd) * 4096 + 3072 + aoff)));      \
        asm volatile("s_waitcnt lgkmcnt(0)");                                  \
        __builtin_amdgcn_sched_barrier(0);                                     \
        if (DO_STAGE) STAGE((tt) + 4, dd);                                     \
        bf16x8 bv;                                                             \
        bv[0] = (__bf16)rA[0]; bv[1] = (__bf16)rA[1];                          \
        bv[2] = (__bf16)rA[2]; bv[3] = (__bf16)rA[3];                          \
        bv[4] = (__bf16)rB[0]; bv[5] = (__bf16)rB[1];                          \
        bv[6] = (__bf16)rB[2]; bv[7] = (__bf16)rB[3];                          \
        acc0 = __builtin_amdgcn_mfma_f32_16x16x32_bf16(av0, bv, acc0, 0, 0, 0);\
        acc1 = __builtin_amdgcn_mfma_f32_16x16x32_bf16(av1, bv, acc1, 0, 0, 0);\
    }

    f32x4 acc0 = {0.f, 0.f, 0.f, 0.f};
    f32x4 acc1 = {0.f, 0.f, 0.f, 0.f};

    STAGE(0, 0); STAGE(1, 1); STAGE(2, 2); STAGE(3, 3);

    for (int t = 0; t < 28; t += 4) {
        ITER(t + 0, 0, 12, 1);
        ITER(t + 1, 1, 12, 1);
        ITER(t + 2, 2, 12, 1);
        ITER(t + 3, 3, 12, 1);
    }
    ITER(28, 0, 12, 0);
    ITER(29, 1, 8,  0);
    ITER(30, 2, 4,  0);
    ITER(31, 3, 0,  0);
#undef ITER
#undef STAGE

    // C/D: col(pos) = lane&15, row(batch) = (lane>>4)*4 + reg
    const int pcol  = p0 + row;
    const int brow0 = g * 4;
    #pragma unroll
    for (int r = 0; r < 4; ++r) {
        ext[(size_t)(brow0 + r) * NPOS + pcol]      = acc0[r];
        ext[(size_t)(16 + brow0 + r) * NPOS + pcol] = acc1[r];
    }
}

// ---------------- combine: ext + cpt + sigmoid dynamics ----------------
__global__ __launch_bounds__(256) void combine_kernel(
    const float* __restrict__ na_v, const float* __restrict__ na_a,
    const float* __restrict__ na_m, const float* __restrict__ ws,
    float* __restrict__ out)
{
    const int npq = NPOS >> 2;
    const int t = blockIdx.x * 256 + threadIdx.x;
    if (t >= BB * npq) return;
    const int b  = t / npq;
    const int p0 = (t - b * npq) << 2;

    float4 ev  = *(const float4*)&ws[EXTV_OFF  + (size_t)b * NPOS + p0];
    float4 ea0 = *(const float4*)&ws[EXTA0_OFF + (size_t)b * NPOS + p0];
    float4 ea1 = *(const float4*)&ws[EXTA1_OFF + (size_t)b * NPOS + p0];
    float4 ea = {ea0.x + ea1.x, ea0.y + ea1.y, ea0.z + ea1.z, ea0.w + ea1.w};
    const float* cpt = ws + CPT_OFF;
    float4 q0 = *(const float4*)&cpt[0 * NPOS + p0];
    float4 q1 = *(const float4*)&cpt[1 * NPOS + p0];
    float4 q2 = *(const float4*)&cpt[2 * NPOS + p0];
    float4 q3 = *(const float4*)&cpt[3 * NPOS + p0];
    float4 q4 = *(const float4*)&cpt[4 * NPOS + p0];
    float4 q5 = *(const float4*)&cpt[5 * NPOS + p0];
    float4 nv = *(const float4*)&na_v[p0];
    float4 na = *(const float4*)&na_a[p0];
    float4 nm = *(const float4*)&na_m[p0];

    float evs[4] = {ev.x, ev.y, ev.z, ev.w};
    float eas[4] = {ea.x, ea.y, ea.z, ea.w};
    float nbv[4] = {q0.x + q1.x, q0.y + q1.y, q0.z + q1.z, q0.w + q1.w};
    float nba[4] = {q2.x + q3.x, q2.y + q3.y, q2.z + q3.z, q2.w + q3.w};
    float nbm[4] = {q4.x + q5.x, q4.y + q5.y, q4.z + q5.z, q4.w + q5.w};
    float nvs[4] = {nv.x, nv.y, nv.z, nv.w};
    float nas[4] = {na.x, na.y, na.z, na.w};
    float nms[4] = {nm.x, nm.y, nm.z, nm.w};

    float4 o;
    float* os = (float*)&o;
    #pragma unroll
    for (int u = 0; u < 4; u++) {
        const float xv = (evs[u] + nbv[u] - 3.0f + nms[u]) * 0.3f;
        const float nav_new = nvs[u] * (2.f / 3.f) + (1.f / 3.f) / (1.f + __expf(-xv));
        const float xa = (eas[u] + nba[u] - 3.0f + nms[u]) * 0.3f;
        const float naa_new = nas[u] * (2.f / 3.f) + (1.f / 3.f) / (1.f + __expf(-xa));
        const float xm = (7.0f * nav_new + 3.0f * naa_new + nbm[u] - 3.0f) * 0.3f;
        os[u] = nms[u] * (2.f / 3.f) + (1.f / 3.f) / (1.f + __expf(-xm));
    }
    *(float4*)&out[(size_t)b * NPOS + p0] = o;
}

extern "C" void kernel_launch(void* const* d_in, const int* in_sizes, int n_in,
                              void* d_out, int out_size, void* d_ws, size_t ws_size,
                              hipStream_t stream) {
    const float* video = (const float*)d_in[0];
    const float* audio = (const float*)d_in[1];
    const float* rf_v  = (const float*)d_in[2];
    const float* rf_a  = (const float*)d_in[3];
    const float* na_v  = (const float*)d_in[4];
    const float* na_a  = (const float*)d_in[5];
    const float* na_m  = (const float*)d_in[6];
    float* ws  = (float*)d_ws;
    float* out = (float*)d_out;

    nbT_kernel<<<72, 256, 0, stream>>>(na_v, na_a, na_m, video, audio, ws);
    ext_mfma<<<JOBS_A + 576, 64, 0, stream>>>(rf_v, rf_a, ws);
    combine_kernel<<<(BB * NPOS / 4 + 255) / 256, 256, 0, stream>>>(
        na_v, na_a, na_m, ws, out);
}

// Round 11
// 37.781 us; speedup vs baseline: 1.2541x; 1.0614x over previous
//
#include <hip/hip_runtime.h>
#include <math.h>

#define NN   96
#define NPOS (96*96)   // 9216
#define BB   32
#define KV   1024
#define KA   2048

// ws layout (float offsets)
#define EXTV_OFF  0
#define EXTA0_OFF (BB*NPOS)            // 294912
#define EXTA1_OFF (2*BB*NPOS)          // 589824
#define CPT_OFF   (3*BB*NPOS)          // 884736
#define AFV_OFF   (CPT_OFF + 6*NPOS)   // 940032
#define AFV_SLOTS ((KV/32)*2*64)       // 4096 16B-slots
#define AFA_OFF   (AFV_OFF + AFV_SLOTS*4)  // 956416
#define AFA_SLOTS ((KA/32)*2*64)       // 8192
// total ws ~ 4 MB

typedef __bf16 bf16x8 __attribute__((ext_vector_type(8)));
typedef __bf16 bf16x4 __attribute__((ext_vector_type(4)));
typedef float  f32x4  __attribute__((ext_vector_type(4)));

// ---------------- nb (separable DoG) + vid/aud -> bf16 A-fragment pack ----------------
__global__ __launch_bounds__(256) void nbT_kernel(
    const float* __restrict__ na_v, const float* __restrict__ na_a,
    const float* __restrict__ na_m, const float* __restrict__ video,
    const float* __restrict__ audio, float* __restrict__ ws)
{
    __shared__ float G[96][100];
    __shared__ float act_s[96][100];
    __shared__ float T1t[24][100];

    if (blockIdx.x >= 24) {
        // A-fragment pack: A[16x32] lane layout row=l&15, k=(l>>4)*8+j
        const int e = (blockIdx.x - 24) * 256 + threadIdx.x;   // 0..12287
        const float* src; bf16x8* dst; int K, el;
        if (e < AFV_SLOTS) { src = video; K = KV; dst = (bf16x8*)(ws + AFV_OFF); el = e; }
        else               { src = audio; K = KA; dst = (bf16x8*)(ws + AFA_OFF); el = e - AFV_SLOTS; }
        const int l  = el & 63;
        const int hb = (el >> 6) & 1;
        const int sg = el >> 7;
        const int b  = hb * 16 + (l & 15);
        const int k0 = sg * 32 + ((l >> 4) << 3);
        const float4 f0 = *(const float4*)&src[(size_t)b * K + k0];
        const float4 f1 = *(const float4*)&src[(size_t)b * K + k0 + 4];
        bf16x8 v;
        v[0] = (__bf16)f0.x; v[1] = (__bf16)f0.y; v[2] = (__bf16)f0.z; v[3] = (__bf16)f0.w;
        v[4] = (__bf16)f1.x; v[5] = (__bf16)f1.y; v[6] = (__bf16)f1.z; v[7] = (__bf16)f1.w;
        dst[el] = v;
        return;
    }

    const int c  = blockIdx.x >> 2;
    const int js = (blockIdx.x & 3) * 24;
    float l, s;
    if      (c == 0) { l =  1.60f; s = 3.5f;  }
    else if (c == 1) { l = -1.23f; s = 6.3f;  }
    else if (c == 2) { l =  1.00f; s = 5.3f;  }
    else if (c == 3) { l = -0.80f; s = 11.8f; }
    else if (c == 4) { l =  3.80f; s = 3.5f;  }
    else             { l = -3.30f; s = 6.2f;  }
    const float s2 = s * s;
    const int f = c >> 1;
    const float* act = (f == 0) ? na_v : (f == 1) ? na_a : na_m;
    const int tid = threadIdx.x;
    float* cpt = ws + CPT_OFF;

    for (int idx = tid; idx < 9216; idx += 256) {
        int j = idx / 96, k = idx - j * 96;
        int d = abs(j - k); d = min(d, 96 - d);
        G[j][k]     = __expf(-0.5f * (float)(d * d) * s2);
        act_s[j][k] = act[idx];
    }
    __syncthreads();

    const int hg3 = (tid >> 3) * 3;
    const int jl3 = (tid & 7) * 3;

    float t1[3][3] = {};
    for (int k0 = 0; k0 < 96; k0 += 4) {
        float4 av[3], gv[3];
        #pragma unroll
        for (int r = 0; r < 3; r++) {
            av[r] = *(const float4*)&act_s[hg3 + r][k0];
            gv[r] = *(const float4*)&G[js + jl3 + r][k0];
        }
        #pragma unroll
        for (int hh = 0; hh < 3; hh++)
            #pragma unroll
            for (int jj = 0; jj < 3; jj++)
                t1[hh][jj] += av[hh].x * gv[jj].x + av[hh].y * gv[jj].y
                            + av[hh].z * gv[jj].z + av[hh].w * gv[jj].w;
    }
    #pragma unroll
    for (int hh = 0; hh < 3; hh++)
        #pragma unroll
        for (int jj = 0; jj < 3; jj++)
            T1t[jl3 + jj][hg3 + hh] = t1[hh][jj];
    __syncthreads();

    float o[3][3] = {};
    for (int h0 = 0; h0 < 96; h0 += 4) {
        float4 gv[3], tv[3];
        #pragma unroll
        for (int r = 0; r < 3; r++) {
            gv[r] = *(const float4*)&G[hg3 + r][h0];
            tv[r] = *(const float4*)&T1t[jl3 + r][h0];
        }
        #pragma unroll
        for (int ii = 0; ii < 3; ii++)
            #pragma unroll
            for (int jj = 0; jj < 3; jj++)
                o[ii][jj] += gv[ii].x * tv[jj].x + gv[ii].y * tv[jj].y
                           + gv[ii].z * tv[jj].z + gv[ii].w * tv[jj].w;
    }
    #pragma unroll
    for (int ii = 0; ii < 3; ii++)
        #pragma unroll
        for (int jj = 0; jj < 3; jj++)
            cpt[c * NPOS + (hg3 + ii) * 96 + (js + jl3 + jj)] = l * o[ii][jj];
}

// ---------------- ext GEMM: dense-stream MFMA ----------------
// Block = 16 pos x 1024-k chunk, 256 threads. Staging: 16 loads/thread, each
// load instruction = 256 lanes x float4 = ONE CONTIGUOUS 4KB row-chunk (the
// 6.3 TB/s copy pattern — kills the 4KB-stride channel aliasing that capped
// r1-r10 at ~1.5 TB/s). LDS rows padded to 2064 B (129 granules): reads AND
// writes conflict-free, no swizzle. Compute: wave = (batch-half, k-half),
// 16 MFMA steps; k-halves reduced via 2KB LDS. Latency hidden by block-level
// TLP (4 blocks/CU, 16 waves/CU in mixed stage/compute phases).
#define LDS_ROW 2064
__global__ __launch_bounds__(256, 4) void ext_mfma(
    const float* __restrict__ rf_v, const float* __restrict__ rf_a,
    float* __restrict__ ws)
{
    __shared__ char lds[16 * LDS_ROW + 2048];   // 35072 B
    const int tid = threadIdx.x;
    const int bid = blockIdx.x;

    const float* rf; const bf16x8* af; float* ext; int K, kb, pt;
    if (bid < 1152) {                   // audio: 576 pos-tiles x 2 k-chunks
        const int c = bid / 576; pt = bid - c * 576;
        rf = rf_a; K = KA; kb = c << 10;
        af  = (const bf16x8*)(ws + AFA_OFF);
        ext = ws + EXTA0_OFF + c * (BB * NPOS);
    } else {                            // video: 576 pos-tiles, one chunk
        pt = bid - 1152; rf = rf_v; K = KV; kb = 0;
        af  = (const bf16x8*)(ws + AFV_OFF);
        ext = ws + EXTV_OFF;
    }

    // ---- stage: rows 0..15, one dense 4KB load-instr per row, 8+8 pipelined
    {
        const float* src = rf + (size_t)(pt * 16) * K + kb + tid * 4;
        float4 fa[8];
        #pragma unroll
        for (int j = 0; j < 8; ++j) fa[j] = *(const float4*)(src + (size_t)j * K);
        #pragma unroll
        for (int j = 0; j < 8; ++j) {
            bf16x4 v;
            v[0] = (__bf16)fa[j].x; v[1] = (__bf16)fa[j].y;
            v[2] = (__bf16)fa[j].z; v[3] = (__bf16)fa[j].w;
            *(bf16x4*)(lds + j * LDS_ROW + tid * 8) = v;
        }
        #pragma unroll
        for (int j = 0; j < 8; ++j) fa[j] = *(const float4*)(src + (size_t)(j + 8) * K);
        #pragma unroll
        for (int j = 0; j < 8; ++j) {
            bf16x4 v;
            v[0] = (__bf16)fa[j].x; v[1] = (__bf16)fa[j].y;
            v[2] = (__bf16)fa[j].z; v[3] = (__bf16)fa[j].w;
            *(bf16x4*)(lds + (j + 8) * LDS_ROW + tid * 8) = v;
        }
    }
    __syncthreads();

    // ---- compute: wave = (bh, kh); 16 steps of 16x16x32 over 512 k
    const int l  = tid & 63, w = tid >> 6;
    const int bh = w & 1, kh = w >> 1;
    const bf16x8* ap = af + ((kb >> 5) + (kh << 4)) * 128 + (bh << 6) + l;
    const char*   bp = lds + (l & 15) * LDS_ROW + (kh << 10) + ((l >> 4) << 4);
    f32x4 acc = {0.f, 0.f, 0.f, 0.f};
    #pragma unroll
    for (int s = 0; s < 16; ++s) {
        bf16x8 a = ap[s * 128];                       // L2-hot A fragments
        bf16x8 b = *(const bf16x8*)(bp + s * 64);     // conflict-free ds_read
        acc = __builtin_amdgcn_mfma_f32_16x16x32_bf16(a, b, acc, 0, 0, 0);
    }

    // ---- k-half reduction: kh=1 writes, kh=0 adds and stores
    if (kh) *(f32x4*)(lds + 16 * LDS_ROW + (bh << 10) + l * 16) = acc;
    __syncthreads();
    if (!kh) {
        f32x4 o = *(const f32x4*)(lds + 16 * LDS_ROW + (bh << 10) + l * 16);
        acc += o;
        // C/D: col(pos) = l&15, row(batch) = (l>>4)*4 + reg
        const int pcol = pt * 16 + (l & 15);
        const int br0  = (bh << 4) + ((l >> 4) << 2);
        #pragma unroll
        for (int r = 0; r < 4; ++r)
            ext[(size_t)(br0 + r) * NPOS + pcol] = acc[r];
    }
}

// ---------------- combine: ext + cpt + sigmoid dynamics ----------------
__global__ __launch_bounds__(256) void combine_kernel(
    const float* __restrict__ na_v, const float* __restrict__ na_a,
    const float* __restrict__ na_m, const float* __restrict__ ws,
    float* __restrict__ out)
{
    const int npq = NPOS >> 2;
    const int t = blockIdx.x * 256 + threadIdx.x;
    if (t >= BB * npq) return;
    const int b  = t / npq;
    const int p0 = (t - b * npq) << 2;

    float4 ev  = *(const float4*)&ws[EXTV_OFF  + (size_t)b * NPOS + p0];
    float4 ea0 = *(const float4*)&ws[EXTA0_OFF + (size_t)b * NPOS + p0];
    float4 ea1 = *(const float4*)&ws[EXTA1_OFF + (size_t)b * NPOS + p0];
    float4 ea = {ea0.x + ea1.x, ea0.y + ea1.y, ea0.z + ea1.z, ea0.w + ea1.w};
    const float* cpt = ws + CPT_OFF;
    float4 q0 = *(const float4*)&cpt[0 * NPOS + p0];
    float4 q1 = *(const float4*)&cpt[1 * NPOS + p0];
    float4 q2 = *(const float4*)&cpt[2 * NPOS + p0];
    float4 q3 = *(const float4*)&cpt[3 * NPOS + p0];
    float4 q4 = *(const float4*)&cpt[4 * NPOS + p0];
    float4 q5 = *(const float4*)&cpt[5 * NPOS + p0];
    float4 nv = *(const float4*)&na_v[p0];
    float4 na = *(const float4*)&na_a[p0];
    float4 nm = *(const float4*)&na_m[p0];

    float evs[4] = {ev.x, ev.y, ev.z, ev.w};
    float eas[4] = {ea.x, ea.y, ea.z, ea.w};
    float nbv[4] = {q0.x + q1.x, q0.y + q1.y, q0.z + q1.z, q0.w + q1.w};
    float nba[4] = {q2.x + q3.x, q2.y + q3.y, q2.z + q3.z, q2.w + q3.w};
    float nbm[4] = {q4.x + q5.x, q4.y + q5.y, q4.z + q5.z, q4.w + q5.w};
    float nvs[4] = {nv.x, nv.y, nv.z, nv.w};
    float nas[4] = {na.x, na.y, na.z, na.w};
    float nms[4] = {nm.x, nm.y, nm.z, nm.w};

    float4 o;
    float* os = (float*)&o;
    #pragma unroll
    for (int u = 0; u < 4; u++) {
        const float xv = (evs[u] + nbv[u] - 3.0f + nms[u]) * 0.3f;
        const float nav_new = nvs[u] * (2.f / 3.f) + (1.f / 3.f) / (1.f + __expf(-xv));
        const float xa = (eas[u] + nba[u] - 3.0f + nms[u]) * 0.3f;
        const float naa_new = nas[u] * (2.f / 3.f) + (1.f / 3.f) / (1.f + __expf(-xa));
        const float xm = (7.0f * nav_new + 3.0f * naa_new + nbm[u] - 3.0f) * 0.3f;
        os[u] = nms[u] * (2.f / 3.f) + (1.f / 3.f) / (1.f + __expf(-xm));
    }
    *(float4*)&out[(size_t)b * NPOS + p0] = o;
}

extern "C" void kernel_launch(void* const* d_in, const int* in_sizes, int n_in,
                              void* d_out, int out_size, void* d_ws, size_t ws_size,
                              hipStream_t stream) {
    const float* video = (const float*)d_in[0];
    const float* audio = (const float*)d_in[1];
    const float* rf_v  = (const float*)d_in[2];
    const float* rf_a  = (const float*)d_in[3];
    const float* na_v  = (const float*)d_in[4];
    const float* na_a  = (const float*)d_in[5];
    const float* na_m  = (const float*)d_in[6];
    float* ws  = (float*)d_ws;
    float* out = (float*)d_out;

    nbT_kernel<<<72, 256, 0, stream>>>(na_v, na_a, na_m, video, audio, ws);
    ext_mfma<<<1728, 256, 0, stream>>>(rf_v, rf_a, ws);
    combine_kernel<<<(BB * NPOS / 4 + 255) / 256, 256, 0, stream>>>(
        na_v, na_a, na_m, ws, out);
}